// Round 5
// baseline (336.508 us; speedup 1.0000x reference)
//
#include <hip/hip_runtime.h>
#include <hip/hip_bf16.h>

static constexpr int Nc = 256;
static constexpr float NEGc = -1e30f;
static constexpr float SLOPEc = 0.01f;
static constexpr unsigned NBLK = 256;

using f32x4 = __attribute__((ext_vector_type(4))) float;
using s16x8 = __attribute__((ext_vector_type(8))) short;

__device__ __forceinline__ void mfma16(f32x4& d, s16x8 a, s16x8 b) {
    // D = A(16x32)*B(32x16)+D ; A row=lane&15,k=(lane>>4)*8+reg ; B col=lane&15
    // C/D col=lane&15, row=(lane>>4)*4+reg   (validated rounds 1-4)
    asm("v_mfma_f32_16x16x32_bf16 %0, %1, %2, %0" : "+v"(d) : "v"(a), "v"(b));
}

__device__ __forceinline__ float wredMax(float v) {
#pragma unroll
    for (int o = 32; o; o >>= 1) v = fmaxf(v, __shfl_xor(v, o, 64));
    return v;
}
__device__ __forceinline__ float wredSum(float v) {
#pragma unroll
    for (int o = 32; o; o >>= 1) v += __shfl_xor(v, o, 64);
    return v;
}

__device__ __forceinline__ unsigned packhi(unsigned u1, unsigned u0) {
    return __builtin_amdgcn_perm(u1, u0, 0x07060302u);
}

// Monotonic-counter grid barrier. goal = (#barriers so far)*NBLK.
// Release: __threadfence before arrival (writes back this XCD's caches).
// Acquire: trailing __threadfence after spin (invalidates L1/L2).
__device__ __forceinline__ void gridbar(unsigned* cnt, unsigned goal) {
    __syncthreads();
    if (threadIdx.x == 0) {
        __threadfence();
        atomicAdd(cnt, 1u);
        while (__hip_atomic_load(cnt, __ATOMIC_RELAXED, __HIP_MEMORY_SCOPE_AGENT) < goal)
            __builtin_amdgcn_s_sleep(1);
    }
    __syncthreads();
    __threadfence();
}

// ---------------------------------------------------------------------------
// Weight conversion work item (idx in [0, 79232)). Builds fused split weights
// F = [ W | W@Wa | W@Wb ] (448 cols, layout [k>>3][448][8] hi/lo) and fused
// 448-wide biases [ b | b@Wa | b@Wb+ab1 ].
// ---------------------------------------------------------------------------
__device__ __forceinline__ void convert_item(
    int idx,
    const float* __restrict__ W0, const float* __restrict__ b0,
    const float* __restrict__ W1, const float* __restrict__ b1,
    const float* __restrict__ A1, const float* __restrict__ ab1,
    ushort* __restrict__ F0h, ushort* __restrict__ F0l,
    ushort* __restrict__ F1h, ushort* __restrict__ F1l,
    float* __restrict__ bias0, float* __restrict__ bias1) {
    if (idx < 43520) {
        // W-split sections: [0,30720) W0, [30720,43520) W1
        const float* src; ushort *dh, *dl; int K, ch, c;
        if (idx < 30720) { src = W0; dh = F0h; dl = F0l; K = 768;
                           ch = idx / 320; c = idx - ch * 320; }
        else { int off = idx - 30720; src = W1; dh = F1h; dl = F1l; K = 300;
               ch = off / 320; c = off - ch * 320; }
        float v[8];
#pragma unroll
        for (int e = 0; e < 8; e++) {
            int k = ch * 8 + e;
            v[e] = (k < K && c < 300) ? src[(size_t)k * 300 + c] : 0.f;
        }
        unsigned hu[4], lu[4];
#pragma unroll
        for (int q = 0; q < 4; q++) {
            unsigned u0 = __float_as_uint(v[q * 2]);
            unsigned u1 = __float_as_uint(v[q * 2 + 1]);
            float r0 = v[q * 2] - __uint_as_float(u0 & 0xFFFF0000u);
            float r1 = v[q * 2 + 1] - __uint_as_float(u1 & 0xFFFF0000u);
            hu[q] = packhi(u1, u0);
            lu[q] = packhi(__float_as_uint(r1), __float_as_uint(r0));
        }
        size_t dst = ((size_t)ch * 448 + c) * 8;
        *(uint4*)&dh[dst] = make_uint4(hu[0], hu[1], hu[2], hu[3]);
        *(uint4*)&dl[dst] = make_uint4(lu[0], lu[1], lu[2], lu[3]);
    } else if (idx < 78336) {
        // WA sections: [43520,68096) W0@A1parts, [68096,78336) W1@A1parts
        const float* Wsrc; ushort *dh, *dl; int K, ch, c, eh;
        if (idx < 68096) {
            int off = idx - 43520; Wsrc = W0; dh = F0h; dl = F0l; K = 768;
            ch = off >> 8; int rem = off & 255; c = rem >> 1; eh = rem & 1;
        } else {
            int off = idx - 68096; Wsrc = W1; dh = F1h; dl = F1l; K = 300;
            ch = off >> 8; int rem = off & 255; c = rem >> 1; eh = rem & 1;
        }
        const float* Wr[4]; float val[4];
#pragma unroll
        for (int i = 0; i < 4; i++) {
            int k = ch * 8 + eh * 4 + i;
            int kc = k < K ? k : 0;
            Wr[i] = Wsrc + (size_t)kc * 300;
            val[i] = (k < K) ? 1.f : 0.f;
        }
        const float* a1c = (c < 64) ? (A1 + c) : (A1 + 300 * 64 + (c - 64));
        float acc[4] = {};
        for (int mm = 0; mm < 300; mm++) {
            float av = a1c[(size_t)mm * 64];
#pragma unroll
            for (int i = 0; i < 4; i++) acc[i] += Wr[i][mm] * av;
        }
#pragma unroll
        for (int i = 0; i < 4; i++) acc[i] *= val[i];
        unsigned hu[2], lu[2];
#pragma unroll
        for (int q = 0; q < 2; q++) {
            unsigned u0 = __float_as_uint(acc[q * 2]);
            unsigned u1 = __float_as_uint(acc[q * 2 + 1]);
            float r0 = acc[q * 2] - __uint_as_float(u0 & 0xFFFF0000u);
            float r1 = acc[q * 2 + 1] - __uint_as_float(u1 & 0xFFFF0000u);
            hu[q] = packhi(u1, u0);
            lu[q] = packhi(__float_as_uint(r1), __float_as_uint(r0));
        }
        size_t dst = ((size_t)ch * 448 + 320 + c) * 8 + eh * 4;
        *(uint2*)&dh[dst] = make_uint2(hu[0], hu[1]);
        *(uint2*)&dl[dst] = make_uint2(lu[0], lu[1]);
    } else {
        // bias fold: [78336,79232)
        int off = idx - 78336;
        int layer = off / 448, col = off - layer * 448;
        const float* b = layer ? b1 : b0;
        float v;
        if (col < 320) {
            v = (col < 300) ? b[col] : 0.f;
        } else {
            int cc = col - 320;
            const float* a1c = (cc < 64) ? (A1 + cc) : (A1 + 300 * 64 + (cc - 64));
            float s = 0.f;
            for (int mm = 0; mm < 300; mm++) s += b[mm] * a1c[(size_t)mm * 64];
            v = s + ((cc >= 64) ? ab1[cc - 64] : 0.f);
        }
        (layer ? bias1 : bias0)[col] = v;
    }
}

// ---------------------------------------------------------------------------
// Shared GEMM core: 64x64 tile, split-bf16 3-pass MFMA, 2-phase prefetch.
// ---------------------------------------------------------------------------
__device__ __forceinline__ void gemm_core(
    const float* __restrict__ Ab, const ushort* __restrict__ Whb,
    const ushort* __restrict__ Wlb, int WCOLS, int col0, int Kp,
    f32x4 (&acc)[2][2]) {
    __shared__ __align__(16) short Ah[2048], Al[2048], Bh[2048], Bl[2048];
    const int tid = threadIdx.x;
    const int lane = tid & 63, wave = tid >> 6;
    const int wm = wave >> 1, wn = wave & 1;
    const int m = lane & 15, kch = lane >> 4;
    const int arow = tid >> 2, aoff = (tid & 3) * 8;
    const int bchunk = tid >> 6, bcol = tid & 63;
    const int bsel = (bchunk * 64 + bcol) * 8;
    (void)arow; (void)aoff;

    float fa[8];
    s16x8 bhv, blv;
    *(float4*)&fa[0] = *(const float4*)(Ab);
    *(float4*)&fa[4] = *(const float4*)(Ab + 4);
    {
        size_t boff = (size_t)bchunk * WCOLS * 8 + (size_t)(col0 + bcol) * 8;
        bhv = *(const s16x8*)(Whb + boff);
        blv = *(const s16x8*)(Wlb + boff);
    }

    for (int k0 = 0; k0 < Kp; k0 += 32) {
        __syncthreads();   // prior fragment reads (or prior job) done
#pragma unroll
        for (int q = 0; q < 2; q++) {
            unsigned u0 = __float_as_uint(fa[q * 4 + 0]);
            unsigned u1 = __float_as_uint(fa[q * 4 + 1]);
            unsigned u2 = __float_as_uint(fa[q * 4 + 2]);
            unsigned u3 = __float_as_uint(fa[q * 4 + 3]);
            float r0 = fa[q * 4 + 0] - __uint_as_float(u0 & 0xFFFF0000u);
            float r1 = fa[q * 4 + 1] - __uint_as_float(u1 & 0xFFFF0000u);
            float r2 = fa[q * 4 + 2] - __uint_as_float(u2 & 0xFFFF0000u);
            float r3 = fa[q * 4 + 3] - __uint_as_float(u3 & 0xFFFF0000u);
            uint2 th, tl;
            th.x = packhi(u1, u0); th.y = packhi(u3, u2);
            tl.x = packhi(__float_as_uint(r1), __float_as_uint(r0));
            tl.y = packhi(__float_as_uint(r3), __float_as_uint(r2));
            int kq = ((tid & 3) * 8) + q * 4;
            int base = ((kq >> 3) * 64 + (tid >> 2)) * 8 + (kq & 7);
            *(uint2*)&Ah[base] = th;
            *(uint2*)&Al[base] = tl;
        }
        *(s16x8*)&Bh[bsel] = bhv;
        *(s16x8*)&Bl[bsel] = blv;
        __syncthreads();
        if (k0 + 32 < Kp) {   // prefetch next K-tile (overlaps ds_read+MFMA)
            *(float4*)&fa[0] = *(const float4*)(Ab + k0 + 32);
            *(float4*)&fa[4] = *(const float4*)(Ab + k0 + 36);
            size_t boff = (size_t)(((k0 + 32) >> 3) + bchunk) * WCOLS * 8
                        + (size_t)(col0 + bcol) * 8;
            bhv = *(const s16x8*)(Whb + boff);
            blv = *(const s16x8*)(Wlb + boff);
        }
        s16x8 Afh[2], Afl[2], Bfh[2], Bfl[2];
#pragma unroll
        for (int fr = 0; fr < 2; fr++) {
            int off = (kch * 64 + wm * 32 + fr * 16 + m) * 8;
            Afh[fr] = *(const s16x8*)&Ah[off];
            Afl[fr] = *(const s16x8*)&Al[off];
        }
#pragma unroll
        for (int fc = 0; fc < 2; fc++) {
            int off = ((kch << 6) + wn * 32 + fc * 16 + m) * 8;
            Bfh[fc] = *(const s16x8*)&Bh[off];
            Bfl[fc] = *(const s16x8*)&Bl[off];
        }
#pragma unroll
        for (int fr = 0; fr < 2; fr++)
#pragma unroll
            for (int fc = 0; fc < 2; fc++) {
                mfma16(acc[fr][fc], Afh[fr], Bfh[fc]);
                mfma16(acc[fr][fc], Afl[fr], Bfh[fc]);
                mfma16(acc[fr][fc], Afh[fr], Bfl[fc]);
            }
    }
}

// ---------------------------------------------------------------------------
// X@F job: epilogue routes col<320 -> H hi/lo split, 320-383 -> si fp32,
// 384-447 -> sjT fp32 (transposed, coalesced for scores).
// ---------------------------------------------------------------------------
__device__ __forceinline__ void xf_job(
    const float* __restrict__ X, int Kp,
    const ushort* __restrict__ Fh, const ushort* __restrict__ Fl,
    const float* __restrict__ bias, int row0, int col0,
    ushort* __restrict__ Hh, ushort* __restrict__ Hl,
    float* __restrict__ siOut, float* __restrict__ sjT) {
    const int tid = threadIdx.x;
    const int lane = tid & 63, wave = tid >> 6;
    const int wm = wave >> 1, wn = wave & 1;
    const int m = lane & 15, kch = lane >> 4;
    f32x4 acc[2][2];
#pragma unroll
    for (int i = 0; i < 2; i++)
#pragma unroll
        for (int j = 0; j < 2; j++)
#pragma unroll
            for (int e = 0; e < 4; e++) acc[i][j][e] = 0.f;
    const float* Ab = X + (size_t)(row0 + (tid >> 2)) * Kp + (tid & 3) * 8;
    gemm_core(Ab, Fh, Fl, 448, col0, Kp, acc);
    asm volatile("s_nop 7\ns_nop 7\ns_nop 7" ::);
#pragma unroll
    for (int fr = 0; fr < 2; fr++) {
        int rbase = row0 + wm * 32 + fr * 16 + (kch << 2);
#pragma unroll
        for (int fc = 0; fc < 2; fc++) {
            int col = col0 + wn * 32 + fc * 16 + m;
            float bv = bias[col];
            float vv[4];
#pragma unroll
            for (int e = 0; e < 4; e++) vv[e] = acc[fr][fc][e] + bv;
            if (col < 320) {
                unsigned u0 = __float_as_uint(vv[0]);
                unsigned u1 = __float_as_uint(vv[1]);
                unsigned u2 = __float_as_uint(vv[2]);
                unsigned u3 = __float_as_uint(vv[3]);
                float r0 = vv[0] - __uint_as_float(u0 & 0xFFFF0000u);
                float r1 = vv[1] - __uint_as_float(u1 & 0xFFFF0000u);
                float r2 = vv[2] - __uint_as_float(u2 & 0xFFFF0000u);
                float r3 = vv[3] - __uint_as_float(u3 & 0xFFFF0000u);
                uint2 th, tl;
                th.x = packhi(u1, u0); th.y = packhi(u3, u2);
                tl.x = packhi(__float_as_uint(r1), __float_as_uint(r0));
                tl.y = packhi(__float_as_uint(r3), __float_as_uint(r2));
                int k = rbase & 255, bb = rbase >> 8;
                size_t dst = (size_t)bb * 81920 + ((size_t)(k >> 3) * 320 + col) * 8 + (k & 7);
                *(uint2*)&Hh[dst] = th;
                *(uint2*)&Hl[dst] = tl;
            } else if (col < 384) {
                int cc = col - 320;
#pragma unroll
                for (int e = 0; e < 4; e++)
                    siOut[(size_t)(rbase + e) * 64 + cc] = vv[e];
            } else {
                int cc = col - 384;
                int bb = rbase >> 8, j0 = rbase & 255;
                float4 v4 = make_float4(vv[0], vv[1], vv[2], vv[3]);
                *(float4*)&sjT[((size_t)(bb * 64 + cc)) * Nc + j0] = v4;
            }
        }
    }
}

// ---------------------------------------------------------------------------
// PV job: merged flat-softmax scale prologue + P@H + scaled fp32 write.
// ---------------------------------------------------------------------------
__device__ __forceinline__ void pv_job(
    const float* __restrict__ Pb, const ushort* __restrict__ Hhb,
    const ushort* __restrict__ Hlb, const float* __restrict__ rmxB,
    const float* __restrict__ rsmB, int row0, int col0,
    float* __restrict__ ob, int OS, int colmax) {
    __shared__ float sclS[256];
    __shared__ float mb[4], sb[4];
    const int tid = threadIdx.x;
    const int lane = tid & 63, wave = tid >> 6;
    __syncthreads();   // prior job's sclS reads done
    {
        float mv = rmxB[tid];
        float wmx = wredMax(mv);
        if (!lane) mb[wave] = wmx;
        __syncthreads();
        float M = fmaxf(fmaxf(mb[0], mb[1]), fmaxf(mb[2], mb[3]));
        float ex = expf(mv - M);
        float ws = wredSum(rsmB[tid] * ex);
        if (!lane) sb[wave] = ws;
        __syncthreads();
        float S = sb[0] + sb[1] + sb[2] + sb[3];
        sclS[tid] = ex / S;
    }
    f32x4 acc[2][2];
#pragma unroll
    for (int i = 0; i < 2; i++)
#pragma unroll
        for (int j = 0; j < 2; j++)
#pragma unroll
            for (int e = 0; e < 4; e++) acc[i][j][e] = 0.f;
    const float* Ab = Pb + (size_t)(row0 + (tid >> 2)) * Nc + (tid & 3) * 8;
    gemm_core(Ab, Hhb, Hlb, 320, col0, 256, acc);
    asm volatile("s_nop 7\ns_nop 7\ns_nop 7" ::);
    const int wm = wave >> 1, wn = wave & 1;
    const int m = lane & 15, kch = lane >> 4;
#pragma unroll
    for (int fr = 0; fr < 2; fr++) {
        int rbase = row0 + wm * 32 + fr * 16 + (kch << 2);
#pragma unroll
        for (int fc = 0; fc < 2; fc++) {
            int col = col0 + wn * 32 + fc * 16 + m;
            if (col < colmax) {
#pragma unroll
                for (int e = 0; e < 4; e++)
                    ob[(size_t)(rbase + e) * OS + col] = acc[fr][fc][e] * sclS[rbase + e];
            }
        }
    }
}

// ---------------------------------------------------------------------------
// scores job: e = leaky(a2 . relu(si+sj)), mask, per-row max/sum-exp,
// P = exp(e - rowmax). One job = 8 rows of one batch.
// ---------------------------------------------------------------------------
__device__ __forceinline__ void scores_job(
    const float* __restrict__ si, const float* __restrict__ sjT,
    const float* __restrict__ adj, const float* __restrict__ A2, float ab2v,
    float* __restrict__ P, float* __restrict__ rmx, float* __restrict__ rsm,
    int b, int ic) {
    __shared__ __align__(16) float sis[8][68];
    __shared__ __align__(16) float a2s[64];
    __shared__ __align__(16) float E[8][260];
    const int j = threadIdx.x;
    __syncthreads();   // prior job's LDS reads done
    if (j < 64) a2s[j] = A2[j];
#pragma unroll
    for (int idx = j, t = 0; t < 2; t++, idx += 256) {
        int r = idx >> 6, h = idx & 63;
        sis[r][h] = si[(size_t)(b * Nc + ic * 8 + r) * 64 + h];
    }
    float sv[64];
    const float* sjb = sjT + ((size_t)b << 6) * Nc + j;
#pragma unroll
    for (int h = 0; h < 64; h++) sv[h] = sjb[(size_t)h * Nc];
    __syncthreads();
    float acc[8] = {};
#pragma unroll
    for (int hq = 0; hq < 16; hq++) {
        float4 a2q = *(const float4*)&a2s[hq * 4];
#pragma unroll
        for (int r = 0; r < 8; r++) {
            const float4 siq = *(const float4*)&sis[r][hq * 4];
            acc[r] += a2q.x * fmaxf(siq.x + sv[hq * 4 + 0], 0.f)
                    + a2q.y * fmaxf(siq.y + sv[hq * 4 + 1], 0.f)
                    + a2q.z * fmaxf(siq.z + sv[hq * 4 + 2], 0.f)
                    + a2q.w * fmaxf(siq.w + sv[hq * 4 + 3], 0.f);
        }
    }
    const float* adjp = adj + (size_t)(b * Nc + ic * 8) * Nc + j;
#pragma unroll
    for (int r = 0; r < 8; r++) {
        float e = acc[r] + ab2v;
        e = e > 0.f ? e : SLOPEc * e;
        float a = adjp[(size_t)r * Nc];
        E[r][j] = (a != 0.f) ? e : NEGc;
    }
    __syncthreads();
    int wv = j >> 6, lane = j & 63;
#pragma unroll
    for (int rr = 0; rr < 2; rr++) {
        int r = wv * 2 + rr;
        float4 q = *(const float4*)&E[r][lane * 4];
        float m4 = fmaxf(fmaxf(q.x, q.y), fmaxf(q.z, q.w));
        float rm = wredMax(m4);
        float4 p;
        p.x = expf(q.x - rm); p.y = expf(q.y - rm);
        p.z = expf(q.z - rm); p.w = expf(q.w - rm);
        float rs = wredSum(p.x + p.y + p.z + p.w);
        int gi = ic * 8 + r;
        *(float4*)(P + (size_t)(b * Nc + gi) * Nc + lane * 4) = p;
        if (lane == 0) { rmx[b * Nc + gi] = rm; rsm[b * Nc + gi] = rs; }
    }
}

// ---------------------------------------------------------------------------
__global__ void __launch_bounds__(256) gat_mega(
    const float* __restrict__ adj, const float* __restrict__ feature,
    const float* __restrict__ W0, const float* __restrict__ b0,
    const float* __restrict__ W1, const float* __restrict__ b1,
    const float* __restrict__ A1, const float* __restrict__ ab1,
    const float* __restrict__ A2, const float* __restrict__ ab2,
    float* __restrict__ outp, float* __restrict__ x1,
    float* __restrict__ si, float* __restrict__ sjT,
    float* __restrict__ P, float* __restrict__ rmx, float* __restrict__ rsm,
    float* __restrict__ bias0, float* __restrict__ bias1,
    ushort* __restrict__ F0h, ushort* __restrict__ F0l,
    ushort* __restrict__ F1h, ushort* __restrict__ F1l,
    ushort* __restrict__ Hh, ushort* __restrict__ Hl,
    unsigned* __restrict__ barcnt) {
    const int bid = blockIdx.x;
    const int tid = threadIdx.x;

    // phase 0: weight conversion + algebraic fusion
    for (int idx = bid * 256 + tid; idx < 79232; idx += 65536)
        convert_item(idx, W0, b0, W1, b1, A1, ab1,
                     F0h, F0l, F1h, F1l, bias0, bias1);
    gridbar(barcnt, 1 * NBLK);

    const float ab2v = ab2[0];
    for (int L = 0; L < 2; L++) {
        const float* X = L ? x1 : feature;
        const ushort* Fh = L ? F1h : F0h;
        const ushort* Fl = L ? F1l : F0l;
        const float* bf = L ? bias1 : bias0;
        const int Kp = L ? 320 : 768;

        // [ h-split | si | sjT ] = X @ F + bias   (448 cols, 448 jobs)
        for (int job = bid; job < 448; job += NBLK)
            xf_job(X, Kp, Fh, Fl, bf, (job / 7) * 64, (job % 7) * 64,
                   Hh, Hl, si, sjT);
        gridbar(barcnt, (2 + 3 * L) * NBLK);

        // scores: 512 jobs
        for (int job = bid; job < 512; job += NBLK)
            scores_job(si, sjT, adj, A2, ab2v, P, rmx, rsm, job >> 5, job & 31);
        gridbar(barcnt, (3 + 3 * L) * NBLK);

        // PV: 320 jobs
        float* ob = L ? outp : x1;
        const int OS = L ? 300 : 320;
        for (int job = bid; job < 320; job += NBLK) {
            int c = job % 5, t = job / 5, r = t & 3, b = t >> 2;
            pv_job(P + (size_t)b * 65536, Hh + (size_t)b * 81920,
                   Hl + (size_t)b * 81920, rmx + b * 256, rsm + b * 256,
                   r * 64, c * 64, ob + (size_t)b * 256 * OS, OS, OS);
        }
        if (L == 0) gridbar(barcnt, 4 * NBLK);
    }
}

// ---------------------------------------------------------------------------
extern "C" void kernel_launch(void* const* d_in, const int* in_sizes, int n_in,
                              void* d_out, int out_size, void* d_ws, size_t ws_size,
                              hipStream_t stream) {
    const float* adj     = (const float*)d_in[0];
    const float* feature = (const float*)d_in[1];
    const float* W0      = (const float*)d_in[2];
    const float* b0      = (const float*)d_in[3];
    const float* W1      = (const float*)d_in[4];
    const float* b1      = (const float*)d_in[5];
    const float* A1      = (const float*)d_in[6];
    const float* ab1     = (const float*)d_in[7];
    const float* A2      = (const float*)d_in[8];
    const float* ab2     = (const float*)d_in[9];

    char* ws = (char*)d_ws;
    float*  x1    = (float*)(ws);                  // 4096x320      5,242,880
    float*  si    = (float*)(ws + 5242880);        // 4096x64       1,048,576
    float*  sjT   = (float*)(ws + 6291456);        // 16x64x256     1,048,576
    float*  P     = (float*)(ws + 7340032);        // 16x256x256    4,194,304
    float*  rmx   = (float*)(ws + 11534336);       //               16,384
    float*  rsm   = (float*)(ws + 11550720);       //               16,384
    float*  bias0 = (float*)(ws + 11567104);       //               1,792
    float*  bias1 = (float*)(ws + 11568896);       //               1,792
    ushort* F0h   = (ushort*)(ws + 11570688);      // 96x448x8      688,128
    ushort* F0l   = (ushort*)(ws + 12258816);      //               688,128
    ushort* F1h   = (ushort*)(ws + 12946944);      // 40x448x8      286,720
    ushort* F1l   = (ushort*)(ws + 13233664);      //               286,720
    ushort* Hh    = (ushort*)(ws + 13520384);      // 16x[32][320][8] 2,621,440
    ushort* Hl    = (ushort*)(ws + 16141824);      //               2,621,440
    unsigned* bar = (unsigned*)(ws + 18763264);    // barrier counter (64B)
    float* outp   = (float*)d_out;

    hipMemsetAsync(bar, 0, 64, stream);
    gat_mega<<<dim3(NBLK), dim3(256), 0, stream>>>(
        adj, feature, W0, b0, W1, b1, A1, ab1, A2, ab2,
        outp, x1, si, sjT, P, rmx, rsm, bias0, bias1,
        F0h, F0l, F1h, F1l, Hh, Hl, bar);
}

// Round 6
// 97.035 us; speedup vs baseline: 3.4679x; 3.4679x over previous
//
#include <hip/hip_runtime.h>
#include <hip/hip_bf16.h>

static constexpr int Nc = 256;
static constexpr float NEGc = -1e30f;
static constexpr float SLOPEc = 0.01f;

using f32x4 = __attribute__((ext_vector_type(4))) float;
using s16x8 = __attribute__((ext_vector_type(8))) short;

__device__ __forceinline__ void mfma16(f32x4& d, s16x8 a, s16x8 b) {
    // D = A(16x32)*B(32x16)+D ; A row=lane&15,k=(lane>>4)*8+reg ; B col=lane&15
    // C/D col=lane&15, row=(lane>>4)*4+reg   (validated rounds 1-5)
    asm("v_mfma_f32_16x16x32_bf16 %0, %1, %2, %0" : "+v"(d) : "v"(a), "v"(b));
}

__device__ __forceinline__ float wredMax(float v) {
#pragma unroll
    for (int o = 32; o; o >>= 1) v = fmaxf(v, __shfl_xor(v, o, 64));
    return v;
}
__device__ __forceinline__ float wredSum(float v) {
#pragma unroll
    for (int o = 32; o; o >>= 1) v += __shfl_xor(v, o, 64);
    return v;
}

__device__ __forceinline__ unsigned packhi(unsigned u1, unsigned u0) {
    return __builtin_amdgcn_perm(u1, u0, 0x07060302u);
}

// ---------------------------------------------------------------------------
// convert_all: fused split weights F = [ W | W@Wa | W@Wb ] (448 cols,
// layout [k>>3][448][8] hi/lo) and fused 448-wide biases [ b | b@Wa | b@Wb+ab1 ].
// WA sections: 1 output per thread (4.2x the R4 parallelism).
// items: [0,43520) W-split, [43520,141824) WA0, [141824,182784) WA1,
//        [182784,183680) bias
// ---------------------------------------------------------------------------
__global__ void __launch_bounds__(256) convert_all(
    const float* __restrict__ W0, const float* __restrict__ b0,
    const float* __restrict__ W1, const float* __restrict__ b1,
    const float* __restrict__ A1, const float* __restrict__ ab1,
    ushort* __restrict__ F0h, ushort* __restrict__ F0l,
    ushort* __restrict__ F1h, ushort* __restrict__ F1l,
    float* __restrict__ bias0, float* __restrict__ bias1) {
    int idx = blockIdx.x * 256 + threadIdx.x;
    if (idx >= 183680) return;

    if (idx < 43520) {
        // W-split sections: [0,30720) W0, [30720,43520) W1
        const float* src; ushort *dh, *dl; int K, ch, c;
        if (idx < 30720) { src = W0; dh = F0h; dl = F0l; K = 768;
                           ch = idx / 320; c = idx - ch * 320; }
        else { int off = idx - 30720; src = W1; dh = F1h; dl = F1l; K = 300;
               ch = off / 320; c = off - ch * 320; }
        float v[8];
#pragma unroll
        for (int e = 0; e < 8; e++) {
            int k = ch * 8 + e;
            v[e] = (k < K && c < 300) ? src[(size_t)k * 300 + c] : 0.f;
        }
        unsigned hu[4], lu[4];
#pragma unroll
        for (int q = 0; q < 4; q++) {
            unsigned u0 = __float_as_uint(v[q * 2]);
            unsigned u1 = __float_as_uint(v[q * 2 + 1]);
            float r0 = v[q * 2] - __uint_as_float(u0 & 0xFFFF0000u);
            float r1 = v[q * 2 + 1] - __uint_as_float(u1 & 0xFFFF0000u);
            hu[q] = packhi(u1, u0);
            lu[q] = packhi(__float_as_uint(r1), __float_as_uint(r0));
        }
        size_t dst = ((size_t)ch * 448 + c) * 8;
        *(uint4*)&dh[dst] = make_uint4(hu[0], hu[1], hu[2], hu[3]);
        *(uint4*)&dl[dst] = make_uint4(lu[0], lu[1], lu[2], lu[3]);
    } else if (idx < 182784) {
        // WA sections: one 300-MAC dot per thread.
        // lanes vary c (A1 coalesced), k uniform per 128-group (W broadcast)
        const float* Wsrc; ushort *dh, *dl; int K, idx2;
        if (idx < 141824) { idx2 = idx - 43520; Wsrc = W0; dh = F0h; dl = F0l; K = 768; }
        else { idx2 = idx - 141824; Wsrc = W1; dh = F1h; dl = F1l; K = 300; }
        int k = idx2 >> 7, c = idx2 & 127;
        float accv = 0.f;
        if (k < K) {
            const float* wrow = Wsrc + (size_t)k * 300;
            const float* a1c = (c < 64) ? (A1 + c) : (A1 + 300 * 64 + (c - 64));
            for (int mm = 0; mm < 300; mm += 4) {
                accv += wrow[mm] * a1c[(size_t)mm * 64]
                      + wrow[mm + 1] * a1c[(size_t)(mm + 1) * 64]
                      + wrow[mm + 2] * a1c[(size_t)(mm + 2) * 64]
                      + wrow[mm + 3] * a1c[(size_t)(mm + 3) * 64];
            }
        }
        unsigned u = __float_as_uint(accv);
        float r = accv - __uint_as_float(u & 0xFFFF0000u);
        size_t dst = ((size_t)(k >> 3) * 448 + 320 + c) * 8 + (k & 7);
        dh[dst] = (ushort)(u >> 16);
        dl[dst] = (ushort)(__float_as_uint(r) >> 16);
    } else {
        // bias fold
        int off = idx - 182784;
        int layer = off / 448, col = off - layer * 448;
        const float* b = layer ? b1 : b0;
        float v;
        if (col < 320) {
            v = (col < 300) ? b[col] : 0.f;
        } else {
            int cc = col - 320;
            const float* a1c = (cc < 64) ? (A1 + cc) : (A1 + 300 * 64 + (cc - 64));
            float s = 0.f;
            for (int mm = 0; mm < 300; mm++) s += b[mm] * a1c[(size_t)mm * 64];
            v = s + ((cc >= 64) ? ab1[cc - 64] : 0.f);
        }
        (layer ? bias1 : bias0)[col] = v;
    }
}

// ---------------------------------------------------------------------------
// GEMM core: 64x64 tile, split-bf16 3-pass MFMA, double-buffered LDS,
// ONE barrier per K-step; stage(next) and global loads overlap MFMA(cur).
// ---------------------------------------------------------------------------
__device__ __forceinline__ void gemm_core(
    const float* __restrict__ Ab, const ushort* __restrict__ Whb,
    const ushort* __restrict__ Wlb, int WCOLS, int col0, int Kp,
    f32x4 (&acc)[2][2]) {
    __shared__ __align__(16) short Ah[2][2048], Al[2][2048];
    __shared__ __align__(16) short Bh[2][2048], Bl[2][2048];
    const int tid = threadIdx.x;
    const int lane = tid & 63, wave = tid >> 6;
    const int wm = wave >> 1, wn = wave & 1;
    const int m = lane & 15, kch = lane >> 4;
    const int arow = tid >> 2, aoff = (tid & 3) * 8;
    const int bchunk = tid >> 6, bcol = tid & 63;
    const int bsel = (bchunk * 64 + bcol) * 8;

    float fa[8];
    s16x8 bhv, blv;

    auto loadrg = [&](int kk) {
        *(float4*)&fa[0] = *(const float4*)(Ab + kk);
        *(float4*)&fa[4] = *(const float4*)(Ab + kk + 4);
        size_t boff = (size_t)((kk >> 3) + bchunk) * WCOLS * 8
                    + (size_t)(col0 + bcol) * 8;
        bhv = *(const s16x8*)(Whb + boff);
        blv = *(const s16x8*)(Wlb + boff);
    };
    auto stage = [&](int buf) {
#pragma unroll
        for (int q = 0; q < 2; q++) {
            unsigned u0 = __float_as_uint(fa[q * 4 + 0]);
            unsigned u1 = __float_as_uint(fa[q * 4 + 1]);
            unsigned u2 = __float_as_uint(fa[q * 4 + 2]);
            unsigned u3 = __float_as_uint(fa[q * 4 + 3]);
            float r0 = fa[q * 4 + 0] - __uint_as_float(u0 & 0xFFFF0000u);
            float r1 = fa[q * 4 + 1] - __uint_as_float(u1 & 0xFFFF0000u);
            float r2 = fa[q * 4 + 2] - __uint_as_float(u2 & 0xFFFF0000u);
            float r3 = fa[q * 4 + 3] - __uint_as_float(u3 & 0xFFFF0000u);
            uint2 th, tl;
            th.x = packhi(u1, u0); th.y = packhi(u3, u2);
            tl.x = packhi(__float_as_uint(r1), __float_as_uint(r0));
            tl.y = packhi(__float_as_uint(r3), __float_as_uint(r2));
            int kq = aoff + q * 4;
            int base = ((kq >> 3) * 64 + arow) * 8 + (kq & 7);
            *(uint2*)&Ah[buf][base] = th;
            *(uint2*)&Al[buf][base] = tl;
        }
        *(s16x8*)&Bh[buf][bsel] = bhv;
        *(s16x8*)&Bl[buf][bsel] = blv;
    };

    loadrg(0);
    stage(0);
    if (Kp > 32) loadrg(32);
    __syncthreads();

    for (int k0 = 0; k0 < Kp; k0 += 32) {
        const int cur = (k0 >> 5) & 1;
        s16x8 Afh[2], Afl[2], Bfh[2], Bfl[2];
#pragma unroll
        for (int fr = 0; fr < 2; fr++) {
            int off = (kch * 64 + wm * 32 + fr * 16 + m) * 8;
            Afh[fr] = *(const s16x8*)&Ah[cur][off];
            Afl[fr] = *(const s16x8*)&Al[cur][off];
        }
#pragma unroll
        for (int fc = 0; fc < 2; fc++) {
            int off = ((kch << 6) + wn * 32 + fc * 16 + m) * 8;
            Bfh[fc] = *(const s16x8*)&Bh[cur][off];
            Bfl[fc] = *(const s16x8*)&Bl[cur][off];
        }
        if (k0 + 32 < Kp) {
            stage(cur ^ 1);             // overlaps MFMA below
            if (k0 + 64 < Kp) loadrg(k0 + 64);
        }
#pragma unroll
        for (int fr = 0; fr < 2; fr++)
#pragma unroll
            for (int fc = 0; fc < 2; fc++) {
                mfma16(acc[fr][fc], Afh[fr], Bfh[fc]);
                mfma16(acc[fr][fc], Afl[fr], Bfh[fc]);
                mfma16(acc[fr][fc], Afh[fr], Bfl[fc]);
            }
        __syncthreads();
    }
}

// ---------------------------------------------------------------------------
// xf kernel: [ h-split | si | sjT ] = X @ F + bias   (448 cols)
// ---------------------------------------------------------------------------
__global__ void __launch_bounds__(256) xf_kernel(
    const float* __restrict__ X, int Kp,
    const ushort* __restrict__ Fh, const ushort* __restrict__ Fl,
    const float* __restrict__ bias,
    ushort* __restrict__ Hh, ushort* __restrict__ Hl,
    float* __restrict__ si, float* __restrict__ sjT) {
    const int tid = threadIdx.x;
    const int lane = tid & 63, wave = tid >> 6;
    const int wm = wave >> 1, wn = wave & 1;
    const int m = lane & 15, kch = lane >> 4;
    const int row0 = blockIdx.y * 64, col0 = blockIdx.x * 64;

    f32x4 acc[2][2];
#pragma unroll
    for (int i = 0; i < 2; i++)
#pragma unroll
        for (int j = 0; j < 2; j++)
#pragma unroll
            for (int e = 0; e < 4; e++) acc[i][j][e] = 0.f;

    const float* Ab = X + (size_t)(row0 + (tid >> 2)) * Kp + (tid & 3) * 8;
    gemm_core(Ab, Fh, Fl, 448, col0, Kp, acc);
    asm volatile("s_nop 7\ns_nop 7\ns_nop 7" ::);   // MFMA -> VALU hazard guard

#pragma unroll
    for (int fr = 0; fr < 2; fr++) {
        int rbase = row0 + wm * 32 + fr * 16 + (kch << 2);
#pragma unroll
        for (int fc = 0; fc < 2; fc++) {
            int col = col0 + wn * 32 + fc * 16 + m;
            float bv = bias[col];
            float vv[4];
#pragma unroll
            for (int e = 0; e < 4; e++) vv[e] = acc[fr][fc][e] + bv;
            if (col < 320) {           // h -> hi/lo split, H layout
                unsigned u0 = __float_as_uint(vv[0]);
                unsigned u1 = __float_as_uint(vv[1]);
                unsigned u2 = __float_as_uint(vv[2]);
                unsigned u3 = __float_as_uint(vv[3]);
                float r0 = vv[0] - __uint_as_float(u0 & 0xFFFF0000u);
                float r1 = vv[1] - __uint_as_float(u1 & 0xFFFF0000u);
                float r2 = vv[2] - __uint_as_float(u2 & 0xFFFF0000u);
                float r3 = vv[3] - __uint_as_float(u3 & 0xFFFF0000u);
                uint2 th, tl;
                th.x = packhi(u1, u0); th.y = packhi(u3, u2);
                tl.x = packhi(__float_as_uint(r1), __float_as_uint(r0));
                tl.y = packhi(__float_as_uint(r3), __float_as_uint(r2));
                int k = rbase & 255, bb = rbase >> 8;
                size_t dst = (size_t)bb * 81920 + ((size_t)(k >> 3) * 320 + col) * 8 + (k & 7);
                *(uint2*)&Hh[dst] = th;
                *(uint2*)&Hl[dst] = tl;
            } else if (col < 384) {    // si fp32
                int cc = col - 320;
#pragma unroll
                for (int e = 0; e < 4; e++)
                    si[(size_t)(rbase + e) * 64 + cc] = vv[e];
            } else {                   // sjT fp32 (transposed, coalesced)
                int cc = col - 384;
                int bb = rbase >> 8, j0 = rbase & 255;
                float4 v4 = make_float4(vv[0], vv[1], vv[2], vv[3]);
                *(float4*)&sjT[((size_t)(bb * 64 + cc)) * Nc + j0] = v4;
            }
        }
    }
}

// ---------------------------------------------------------------------------
// scores: e = leaky(a2 . relu(si+sj)), mask, per-row max/sum-exp,
// P = exp(e - rowmax). grid (16 batches, 32 row-tiles of 8).
// ---------------------------------------------------------------------------
__global__ void __launch_bounds__(256) scores_kernel(
    const float* __restrict__ si, const float* __restrict__ sjT,
    const float* __restrict__ adj, const float* __restrict__ A2,
    const float* __restrict__ ab2p,
    float* __restrict__ P, float* __restrict__ rmx, float* __restrict__ rsm) {
    int b = blockIdx.x, ic = blockIdx.y;
    const int j = threadIdx.x;
    __shared__ __align__(16) float sis[8][68];
    __shared__ __align__(16) float a2s[64];
    __shared__ __align__(16) float E[8][260];

    if (j < 64) a2s[j] = A2[j];
#pragma unroll
    for (int idx = j, t = 0; t < 2; t++, idx += 256) {
        int r = idx >> 6, h = idx & 63;
        sis[r][h] = si[(size_t)(b * Nc + ic * 8 + r) * 64 + h];
    }
    float sv[64];
    const float* sjb = sjT + ((size_t)b << 6) * Nc + j;
#pragma unroll
    for (int h = 0; h < 64; h++) sv[h] = sjb[(size_t)h * Nc];
    __syncthreads();

    float acc[8] = {};
#pragma unroll
    for (int hq = 0; hq < 16; hq++) {
        float4 a2q = *(const float4*)&a2s[hq * 4];
#pragma unroll
        for (int r = 0; r < 8; r++) {
            const float4 siq = *(const float4*)&sis[r][hq * 4];
            acc[r] += a2q.x * fmaxf(siq.x + sv[hq * 4 + 0], 0.f)
                    + a2q.y * fmaxf(siq.y + sv[hq * 4 + 1], 0.f)
                    + a2q.z * fmaxf(siq.z + sv[hq * 4 + 2], 0.f)
                    + a2q.w * fmaxf(siq.w + sv[hq * 4 + 3], 0.f);
        }
    }
    float ab2v = ab2p[0];
    const float* adjp = adj + (size_t)(b * Nc + ic * 8) * Nc + j;
#pragma unroll
    for (int r = 0; r < 8; r++) {
        float e = acc[r] + ab2v;
        e = e > 0.f ? e : SLOPEc * e;
        float a = adjp[(size_t)r * Nc];
        E[r][j] = (a != 0.f) ? e : NEGc;
    }
    __syncthreads();
    int wv = j >> 6, lane = j & 63;
#pragma unroll
    for (int rr = 0; rr < 2; rr++) {
        int r = wv * 2 + rr;
        float4 q = *(const float4*)&E[r][lane * 4];
        float m4 = fmaxf(fmaxf(q.x, q.y), fmaxf(q.z, q.w));
        float rm = wredMax(m4);
        float4 p;
        p.x = expf(q.x - rm); p.y = expf(q.y - rm);
        p.z = expf(q.z - rm); p.w = expf(q.w - rm);
        float rs = wredSum(p.x + p.y + p.z + p.w);
        int gi = ic * 8 + r;
        *(float4*)(P + (size_t)(b * Nc + gi) * Nc + lane * 4) = p;
        if (lane == 0) { rmx[b * Nc + gi] = rm; rsm[b * Nc + gi] = rs; }
    }
}

// ---------------------------------------------------------------------------
// pv: out = softmax_scale * (P @ H), flat-softmax merge fused in prologue.
// grid (5 col-tiles, 4 row-tiles, 16 batches)
// ---------------------------------------------------------------------------
__global__ void __launch_bounds__(256) pv_kernel(
    const float* __restrict__ P,
    const ushort* __restrict__ Hh, const ushort* __restrict__ Hl,
    const float* __restrict__ rmx, const float* __restrict__ rsm,
    float* __restrict__ out, int OS) {
    __shared__ float sclS[256];
    __shared__ float mb[4], sb[4];
    const int tid = threadIdx.x;
    const int lane = tid & 63, wave = tid >> 6;
    const int col0 = blockIdx.x * 64, row0 = blockIdx.y * 64;
    const int b = blockIdx.z;

    {   // flat-softmax merge: scale_i = exp(m_i - M)/S
        float mv = rmx[b * 256 + tid];
        float wmx = wredMax(mv);
        if (!lane) mb[wave] = wmx;
        __syncthreads();
        float M = fmaxf(fmaxf(mb[0], mb[1]), fmaxf(mb[2], mb[3]));
        float ex = expf(mv - M);
        float ws = wredSum(rsm[b * 256 + tid] * ex);
        if (!lane) sb[wave] = ws;
        __syncthreads();
        float S = sb[0] + sb[1] + sb[2] + sb[3];
        sclS[tid] = ex / S;
    }

    f32x4 acc[2][2];
#pragma unroll
    for (int i = 0; i < 2; i++)
#pragma unroll
        for (int j = 0; j < 2; j++)
#pragma unroll
            for (int e = 0; e < 4; e++) acc[i][j][e] = 0.f;

    const float* Ab = P + (size_t)b * 65536 + (size_t)(row0 + (tid >> 2)) * Nc + (tid & 3) * 8;
    gemm_core(Ab, Hh + (size_t)b * 81920, Hl + (size_t)b * 81920, 320, col0, 256, acc);
    asm volatile("s_nop 7\ns_nop 7\ns_nop 7" ::);

    const int wm = wave >> 1, wn = wave & 1;
    const int m = lane & 15, kch = lane >> 4;
    float* ob = out + (size_t)b * 256 * OS;
#pragma unroll
    for (int fr = 0; fr < 2; fr++) {
        int rbase = row0 + wm * 32 + fr * 16 + (kch << 2);
#pragma unroll
        for (int fc = 0; fc < 2; fc++) {
            int col = col0 + wn * 32 + fc * 16 + m;
            if (col < OS) {
#pragma unroll
                for (int e = 0; e < 4; e++)
                    ob[(size_t)(rbase + e) * OS + col] = acc[fr][fc][e] * sclS[rbase + e];
            }
        }
    }
}

// ---------------------------------------------------------------------------
extern "C" void kernel_launch(void* const* d_in, const int* in_sizes, int n_in,
                              void* d_out, int out_size, void* d_ws, size_t ws_size,
                              hipStream_t stream) {
    const float* adj     = (const float*)d_in[0];
    const float* feature = (const float*)d_in[1];
    const float* W0      = (const float*)d_in[2];
    const float* b0      = (const float*)d_in[3];
    const float* W1      = (const float*)d_in[4];
    const float* b1      = (const float*)d_in[5];
    const float* A1      = (const float*)d_in[6];
    const float* ab1     = (const float*)d_in[7];
    const float* A2      = (const float*)d_in[8];
    const float* ab2     = (const float*)d_in[9];

    char* ws = (char*)d_ws;
    float*  x1    = (float*)(ws);                  // 4096x320      5,242,880
    float*  si    = (float*)(ws + 5242880);        // 4096x64       1,048,576
    float*  sjT   = (float*)(ws + 6291456);        // 16x64x256     1,048,576
    float*  P     = (float*)(ws + 7340032);        // 16x256x256    4,194,304
    float*  rmx   = (float*)(ws + 11534336);       //               16,384
    float*  rsm   = (float*)(ws + 11550720);       //               16,384
    float*  bias0 = (float*)(ws + 11567104);       //               1,792
    float*  bias1 = (float*)(ws + 11568896);       //               1,792
    ushort* F0h   = (ushort*)(ws + 11570688);      // 96x448x8      688,128
    ushort* F0l   = (ushort*)(ws + 12258816);      //               688,128
    ushort* F1h   = (ushort*)(ws + 12946944);      // 40x448x8      286,720
    ushort* F1l   = (ushort*)(ws + 13233664);      //               286,720
    ushort* Hh    = (ushort*)(ws + 13520384);      // 16x[32][320][8] 2,621,440
    ushort* Hl    = (ushort*)(ws + 16141824);      //               2,621,440
    float* outp   = (float*)d_out;

    convert_all<<<718, 256, 0, stream>>>(W0, b0, W1, b1, A1, ab1,
                                         F0h, F0l, F1h, F1l, bias0, bias1);

    for (int L = 0; L < 2; L++) {
        const float* X = L ? x1 : feature;
        const ushort* Fh = L ? F1h : F0h;
        const ushort* Fl = L ? F1l : F0l;
        const float* bf = L ? bias1 : bias0;
        int Kp = L ? 320 : 768;

        xf_kernel<<<dim3(7, 64), 256, 0, stream>>>(
            X, Kp, Fh, Fl, bf, Hh, Hl, si, sjT);
        scores_kernel<<<dim3(16, 32), 256, 0, stream>>>(
            si, sjT, adj, A2, ab2, P, rmx, rsm);
        pv_kernel<<<dim3(5, 4, 16), 256, 0, stream>>>(
            P, Hh, Hl, rmx, rsm, L ? outp : x1, L ? 300 : 320);
    }
}